// Round 1
// baseline (2118.405 us; speedup 1.0000x reference)
//
#include <hip/hip_runtime.h>
#include <math.h>

#define TOK_I 4096   // I
#define NE 8         // experts
#define NR 16        // lora rank
#define NQ 4096      // q out dim
#define NV 1024      // v out dim
#define LORA_SCALE 2.0f

// One 256-thread block per token. Each thread owns 16 elements of h (kept in
// registers across router + lora_a phases so h is read from HBM exactly once).
__global__ __launch_bounds__(256) void qvlora_fused_kernel(
    const float* __restrict__ h,    // [T, 4096]
    const float* __restrict__ rw,   // [8, 4096]
    const float* __restrict__ qa,   // [8, 4096, 16]
    const float* __restrict__ qb,   // [8, 16, 4096]
    const float* __restrict__ va,   // [8, 4096, 16]
    const float* __restrict__ vb,   // [8, 16, 1024]
    float* __restrict__ qout,       // [T, 4096]
    float* __restrict__ vout)       // [T, 1024]
{
    const int tok  = blockIdx.x;
    const int tid  = threadIdx.x;
    const int lane = tid & 63;
    const int wave = tid >> 6;

    __shared__ float red8[4][8];
    __shared__ float red32[4][32];
    __shared__ float sLow[32];     // [0..15] = low_q, [16..31] = low_v (already * gate)
    __shared__ float sGate;
    __shared__ int   sSel;

    const float4* h4 = (const float4*)(h + (long)tok * TOK_I);

    // ---- load h into registers: 4 float4 = 16 elements per thread ----
    float4 hreg[4];
#pragma unroll
    for (int k = 0; k < 4; ++k) hreg[k] = h4[tid + 256 * k];

    // ---- phase 1: router logits ----
    float lacc[NE];
#pragma unroll
    for (int e = 0; e < NE; ++e) lacc[e] = 0.f;
    const float4* rw4 = (const float4*)rw;
#pragma unroll
    for (int k = 0; k < 4; ++k) {
        float4 hv = hreg[k];
        int f = tid + 256 * k;
#pragma unroll
        for (int e = 0; e < NE; ++e) {
            float4 wv = rw4[e * 1024 + f];
            lacc[e] += hv.x * wv.x + hv.y * wv.y + hv.z * wv.z + hv.w * wv.w;
        }
    }
#pragma unroll
    for (int off = 32; off >= 1; off >>= 1) {
#pragma unroll
        for (int e = 0; e < NE; ++e)
            lacc[e] += __shfl_down(lacc[e], off);
    }
    if (lane == 0) {
#pragma unroll
        for (int e = 0; e < NE; ++e) red8[wave][e] = lacc[e];
    }
    __syncthreads();

    if (tid == 0) {
        float lg[NE];
#pragma unroll
        for (int e = 0; e < NE; ++e)
            lg[e] = red8[0][e] + red8[1][e] + red8[2][e] + red8[3][e];
        int best = 0;
        float mx = lg[0];
#pragma unroll
        for (int e = 1; e < NE; ++e) {
            if (lg[e] > mx) { mx = lg[e]; best = e; }   // first-occurrence argmax
        }
        float s = 0.f;
#pragma unroll
        for (int e = 0; e < NE; ++e) s += __expf(lg[e] - mx);
        sSel  = best;
        sGate = LORA_SCALE / s;   // max softmax prob = 1/s, times lora scale
    }
    __syncthreads();

    const int e = sSel;

    // ---- phase 2: low = (h @ lora_a[e]) for q and v ----
    float acc[32];
#pragma unroll
    for (int c = 0; c < 32; ++c) acc[c] = 0.f;
    const float4* qa4 = (const float4*)(qa + (long)e * TOK_I * NR);
    const float4* va4 = (const float4*)(va + (long)e * TOK_I * NR);
#pragma unroll
    for (int k = 0; k < 4; ++k) {
        float4 hv = hreg[k];
        float he[4] = {hv.x, hv.y, hv.z, hv.w};
        int i0 = 4 * (tid + 256 * k);   // element index of hv.x
#pragma unroll
        for (int d = 0; d < 4; ++d) {
            int row4 = (i0 + d) * 4;    // float4 index of row start (16 floats/row)
#pragma unroll
            for (int r4 = 0; r4 < 4; ++r4) {
                float4 wq = qa4[row4 + r4];
                float4 wv = va4[row4 + r4];
                acc[4 * r4 + 0]      += he[d] * wq.x;
                acc[4 * r4 + 1]      += he[d] * wq.y;
                acc[4 * r4 + 2]      += he[d] * wq.z;
                acc[4 * r4 + 3]      += he[d] * wq.w;
                acc[16 + 4 * r4 + 0] += he[d] * wv.x;
                acc[16 + 4 * r4 + 1] += he[d] * wv.y;
                acc[16 + 4 * r4 + 2] += he[d] * wv.z;
                acc[16 + 4 * r4 + 3] += he[d] * wv.w;
            }
        }
    }
#pragma unroll
    for (int off = 32; off >= 1; off >>= 1) {
#pragma unroll
        for (int c = 0; c < 32; ++c)
            acc[c] += __shfl_down(acc[c], off);
    }
    if (lane == 0) {
#pragma unroll
        for (int c = 0; c < 32; ++c) red32[wave][c] = acc[c];
    }
    __syncthreads();
    if (tid < 32) {
        float v = red32[0][tid] + red32[1][tid] + red32[2][tid] + red32[3][tid];
        sLow[tid] = v * sGate;
    }
    __syncthreads();

    // ---- phase 3: expansion low @ lora_b[e], coalesced float4 stores ----
    float lq[NR], lv[NR];
#pragma unroll
    for (int r = 0; r < NR; ++r) { lq[r] = sLow[r]; lv[r] = sLow[16 + r]; }

    const float4* qb4 = (const float4*)(qb + (long)e * NR * NQ);
    const float4* vb4 = (const float4*)(vb + (long)e * NR * NV);
    float4* qo4 = (float4*)(qout + (long)tok * NQ);
    float4* vo4 = (float4*)(vout + (long)tok * NV);

    // v_delta: 1024 = 256 threads * float4
    {
        float4 o = {0.f, 0.f, 0.f, 0.f};
#pragma unroll
        for (int r = 0; r < NR; ++r) {
            float4 w = vb4[r * 256 + tid];
            o.x += lv[r] * w.x; o.y += lv[r] * w.y;
            o.z += lv[r] * w.z; o.w += lv[r] * w.w;
        }
        vo4[tid] = o;
    }
    // q_delta: 4096 = 4 * (256 threads * float4)
#pragma unroll
    for (int m = 0; m < 4; ++m) {
        float4 o = {0.f, 0.f, 0.f, 0.f};
        int f = tid + 256 * m;
#pragma unroll
        for (int r = 0; r < NR; ++r) {
            float4 w = qb4[r * 1024 + f];
            o.x += lq[r] * w.x; o.y += lq[r] * w.y;
            o.z += lq[r] * w.z; o.w += lq[r] * w.w;
        }
        qo4[f] = o;
    }
}

extern "C" void kernel_launch(void* const* d_in, const int* in_sizes, int n_in,
                              void* d_out, int out_size, void* d_ws, size_t ws_size,
                              hipStream_t stream) {
    const float* h  = (const float*)d_in[0];
    const float* rw = (const float*)d_in[1];
    const float* qa = (const float*)d_in[2];
    const float* qb = (const float*)d_in[3];
    const float* va = (const float*)d_in[4];
    const float* vb = (const float*)d_in[5];
    float* out = (float*)d_out;

    const int T = in_sizes[0] / TOK_I;   // 16384 tokens
    float* qout = out;
    float* vout = out + (long)T * NQ;

    qvlora_fused_kernel<<<T, 256, 0, stream>>>(h, rw, qa, qb, va, vb, qout, vout);
}